// Round 1
// baseline (689.853 us; speedup 1.0000x reference)
//
#include <hip/hip_runtime.h>
#include <hip/hip_bf16.h>

typedef __attribute__((ext_vector_type(4))) float f32x4;
typedef __attribute__((ext_vector_type(8))) short short8;
typedef __attribute__((ext_vector_type(4))) unsigned short ushx4;

#define B_SZ 2
#define T_SZ 2048
#define H_SZ 16
#define DH 128
#define DM 2048
#define M_SZ 4096   // B*T
#define N1 6144     // 3*DM
#define KD 2048

static __device__ __forceinline__ unsigned short f2bf(float f) {
  union { float f; unsigned int u; } v; v.f = f;
  unsigned int r = v.u + 0x7fffu + ((v.u >> 16) & 1u);
  return (unsigned short)(r >> 16);
}
static __device__ __forceinline__ float bf2f(unsigned int u) {
  union { unsigned int u; float f; } v; v.u = u << 16; return v.f;
}

#define ASYNC_COPY16(gsrc, ldst) \
  __builtin_amdgcn_global_load_lds((const __attribute__((address_space(1))) void*)(gsrc), \
                                   (__attribute__((address_space(3))) void*)(ldst), 16, 0, 0)

// ---------------- cast fp32 -> bf16 ----------------
__global__ __launch_bounds__(256) void cast_f32_bf16(const float* __restrict__ in,
                                                     unsigned short* __restrict__ out, int n4) {
  int i = blockIdx.x * 256 + threadIdx.x;
  if (i >= n4) return;
  float4 v = ((const float4*)in)[i];
  ushx4 o;
  o[0] = f2bf(v.x); o[1] = f2bf(v.y); o[2] = f2bf(v.z); o[3] = f2bf(v.w);
  ((ushx4*)out)[i] = o;
}

// ---------------- rope tables ----------------
__global__ __launch_bounds__(64) void rope_table(float* __restrict__ cosb, float* __restrict__ sinb) {
  int t = blockIdx.x;
  int i = threadIdx.x;  // 0..63
  float inv = powf(10000.0f, -(float)i / 64.0f);
  float ang = (float)t * inv;
  cosb[t * 64 + i] = cosf(ang);
  sinb[t * 64 + i] = sinf(ang);
}

// ---------------- GEMM: C[m][n] = sum_k A[m][k] * Bt[n][k]  (both K-major bf16) ----------------
template <bool BF16OUT>
__global__ __launch_bounds__(256) void gemm_bt(const unsigned short* __restrict__ A,
                                               const unsigned short* __restrict__ Bt,
                                               void* __restrict__ Cout,
                                               int M, int N, int K) {
  __shared__ unsigned short As[128 * 32];
  __shared__ unsigned short Bs[128 * 32];
  const int tid = threadIdx.x;
  const int lane = tid & 63;
  const int wave = tid >> 6;
  const int wm = wave >> 1, wn = wave & 1;
  const int m0 = blockIdx.y * 128, n0 = blockIdx.x * 128;
  const int r = lane & 15, q = lane >> 4;

  f32x4 acc[4][4];
#pragma unroll
  for (int i = 0; i < 4; i++)
#pragma unroll
    for (int j = 0; j < 4; j++) acc[i][j] = (f32x4)0.0f;

  const int c0 = tid, c1 = tid + 256;
  const int row0 = c0 >> 2, kc0 = c0 & 3;
  const int row1 = c1 >> 2, kc1 = c1 & 3;

  for (int k0 = 0; k0 < K; k0 += 32) {
    __syncthreads();
    ASYNC_COPY16(A + (size_t)(m0 + row0) * K + k0 + kc0 * 8, &As[c0 * 8]);
    ASYNC_COPY16(A + (size_t)(m0 + row1) * K + k0 + kc1 * 8, &As[c1 * 8]);
    ASYNC_COPY16(Bt + (size_t)(n0 + row0) * K + k0 + kc0 * 8, &Bs[c0 * 8]);
    ASYNC_COPY16(Bt + (size_t)(n0 + row1) * K + k0 + kc1 * 8, &Bs[c1 * 8]);
    __syncthreads();

    short8 a[4], b[4];
#pragma unroll
    for (int mf = 0; mf < 4; mf++)
      a[mf] = *(const short8*)&As[(wm * 64 + mf * 16 + r) * 32 + q * 8];
#pragma unroll
    for (int nf = 0; nf < 4; nf++)
      b[nf] = *(const short8*)&Bs[(wn * 64 + nf * 16 + r) * 32 + q * 8];
#pragma unroll
    for (int mf = 0; mf < 4; mf++)
#pragma unroll
      for (int nf = 0; nf < 4; nf++)
        acc[mf][nf] = __builtin_amdgcn_mfma_f32_16x16x32_bf16(a[mf], b[nf], acc[mf][nf], 0, 0, 0);
  }

#pragma unroll
  for (int mf = 0; mf < 4; mf++) {
#pragma unroll
    for (int nf = 0; nf < 4; nf++) {
#pragma unroll
      for (int reg = 0; reg < 4; reg++) {
        int row = m0 + wm * 64 + mf * 16 + q * 4 + reg;
        int col = n0 + wn * 64 + nf * 16 + r;
        if (BF16OUT)
          ((unsigned short*)Cout)[(size_t)row * N + col] = f2bf(acc[mf][nf][reg]);
        else
          ((float*)Cout)[(size_t)row * N + col] = acc[mf][nf][reg];
      }
    }
  }
}

// ---------------- RoPE + scatter q,k into (B,H,T,DH) ----------------
__global__ __launch_bounds__(256) void rope_scatter_qk(const unsigned short* __restrict__ qkv,
                                                       const float* __restrict__ cosb,
                                                       const float* __restrict__ sinb,
                                                       unsigned short* __restrict__ qb,
                                                       unsigned short* __restrict__ kb) {
  int idx = blockIdx.x * 256 + threadIdx.x;   // 0 .. 4096*1024-1
  int m = idx >> 10;        // row in [0,4096)
  int p = idx & 1023;       // pair index within 2048 cols
  int h = p >> 6, i = p & 63;
  int t = m & (T_SZ - 1);
  int b = m >> 11;
  float c = cosb[t * 64 + i], s = sinb[t * 64 + i];
  size_t dst = (((size_t)(b * H_SZ + h) * T_SZ + t) * DH) + 2 * i;

  // Q
  unsigned int v = *(const unsigned int*)&qkv[(size_t)m * N1 + h * DH + 2 * i];
  float x1 = bf2f(v & 0xffffu), x2 = bf2f(v >> 16);
  float r1 = x1 * c - x2 * s, r2 = x1 * s + x2 * c;
  *(unsigned int*)&qb[dst] = (unsigned int)f2bf(r1) | ((unsigned int)f2bf(r2) << 16);
  // K
  v = *(const unsigned int*)&qkv[(size_t)m * N1 + DM + h * DH + 2 * i];
  x1 = bf2f(v & 0xffffu); x2 = bf2f(v >> 16);
  r1 = x1 * c - x2 * s; r2 = x1 * s + x2 * c;
  *(unsigned int*)&kb[dst] = (unsigned int)f2bf(r1) | ((unsigned int)f2bf(r2) << 16);
}

// ---------------- V transpose into (B,H,DH,T) ----------------
__global__ __launch_bounds__(256) void v_transpose(const unsigned short* __restrict__ qkv,
                                                   unsigned short* __restrict__ vt) {
  __shared__ unsigned short tile[32][34];
  int bh = blockIdx.z, dblk = blockIdx.y, tblk = blockIdx.x;
  int b = bh >> 4, h = bh & 15;
  int tx = threadIdx.x & 31;
  int ty4 = threadIdx.x >> 5;  // 0..7
#pragma unroll
  for (int rr = 0; rr < 4; rr++) {
    int trow = ty4 * 4 + rr;
    int m = b * T_SZ + tblk * 32 + trow;
    tile[trow][tx] = qkv[(size_t)m * N1 + 2 * DM + h * DH + dblk * 32 + tx];
  }
  __syncthreads();
#pragma unroll
  for (int rr = 0; rr < 4; rr++) {
    int drow = ty4 * 4 + rr;
    vt[((size_t)bh * DH + dblk * 32 + drow) * T_SZ + tblk * 32 + tx] = tile[tx][drow];
  }
}

// ---------------- causal flash attention: 1 wave = 16 q rows ----------------
__global__ __launch_bounds__(64) void attn_fwd(const unsigned short* __restrict__ qb,
                                               const unsigned short* __restrict__ kb,
                                               const unsigned short* __restrict__ vt,
                                               unsigned short* __restrict__ of) {
  __shared__ unsigned short P_lds[16 * 72];
  const int lane = threadIdx.x;
  const int bh = blockIdx.y;
  const int q0 = blockIdx.x * 16;
  const int b = bh >> 4, h = bh & 15;
  const int r = lane & 15, q = lane >> 4;
  const float scale = 0.08838834764831845f;  // 1/sqrt(128)

  const unsigned short* Qp = qb + ((size_t)bh * T_SZ + q0) * DH;
  const unsigned short* Kbase = kb + (size_t)bh * T_SZ * DH;
  const unsigned short* Vbase = vt + (size_t)bh * DH * T_SZ;

  short8 qf[4];
#pragma unroll
  for (int c = 0; c < 4; c++) qf[c] = *(const short8*)(Qp + r * DH + c * 32 + q * 8);

  float m_run[4], l_run[4];
  f32x4 oacc[8];
#pragma unroll
  for (int i = 0; i < 4; i++) { m_run[i] = -1e30f; l_run[i] = 0.f; }
#pragma unroll
  for (int i = 0; i < 8; i++) oacc[i] = (f32x4)0.f;

  for (int kv0 = 0; kv0 <= q0 + 15; kv0 += 64) {
    f32x4 S[4];
#pragma unroll
    for (int nf = 0; nf < 4; nf++) S[nf] = (f32x4)0.f;
#pragma unroll
    for (int nf = 0; nf < 4; nf++) {
#pragma unroll
      for (int c = 0; c < 4; c++) {
        short8 kf = *(const short8*)(Kbase + (size_t)(kv0 + nf * 16 + r) * DH + c * 32 + q * 8);
        S[nf] = __builtin_amdgcn_mfma_f32_16x16x32_bf16(qf[c], kf, S[nf], 0, 0, 0);
      }
    }
    float Sv[4][4];
    const bool need_mask = (kv0 + 63 > q0);
#pragma unroll
    for (int nf = 0; nf < 4; nf++) {
#pragma unroll
      for (int reg = 0; reg < 4; reg++) {
        float v = S[nf][reg] * scale;
        if (need_mask) {
          int col = kv0 + nf * 16 + r;
          int row = q0 + q * 4 + reg;
          if (col > row) v = -1e30f;
        }
        Sv[nf][reg] = v;
      }
    }
    float pmax[4], sc_old[4], rsum[4];
#pragma unroll
    for (int reg = 0; reg < 4; reg++) {
      float v = fmaxf(fmaxf(Sv[0][reg], Sv[1][reg]), fmaxf(Sv[2][reg], Sv[3][reg]));
#pragma unroll
      for (int s = 1; s < 16; s <<= 1) v = fmaxf(v, __shfl_xor(v, s));
      pmax[reg] = v;
    }
#pragma unroll
    for (int reg = 0; reg < 4; reg++) {
      float mn = fmaxf(m_run[reg], pmax[reg]);
      sc_old[reg] = __expf(m_run[reg] - mn);
      m_run[reg] = mn;
      rsum[reg] = 0.f;
    }
    __syncthreads();  // protect P_lds reads from previous tile
#pragma unroll
    for (int nf = 0; nf < 4; nf++) {
#pragma unroll
      for (int reg = 0; reg < 4; reg++) {
        float p = __expf(Sv[nf][reg] - m_run[reg]);
        rsum[reg] += p;
        P_lds[(q * 4 + reg) * 72 + nf * 16 + r] = f2bf(p);
      }
    }
    __syncthreads();
#pragma unroll
    for (int reg = 0; reg < 4; reg++) {
      float v = rsum[reg];
#pragma unroll
      for (int s = 1; s < 16; s <<= 1) v += __shfl_xor(v, s);
      l_run[reg] = l_run[reg] * sc_old[reg] + v;
    }
#pragma unroll
    for (int df = 0; df < 8; df++)
#pragma unroll
      for (int reg = 0; reg < 4; reg++) oacc[df][reg] *= sc_old[reg];

    short8 pa[2];
#pragma unroll
    for (int kc = 0; kc < 2; kc++) pa[kc] = *(const short8*)&P_lds[r * 72 + kc * 32 + q * 8];
#pragma unroll
    for (int df = 0; df < 8; df++) {
#pragma unroll
      for (int kc = 0; kc < 2; kc++) {
        short8 vf = *(const short8*)(Vbase + (size_t)(df * 16 + r) * T_SZ + kv0 + kc * 32 + q * 8);
        oacc[df] = __builtin_amdgcn_mfma_f32_16x16x32_bf16(pa[kc], vf, oacc[df], 0, 0, 0);
      }
    }
  }

#pragma unroll
  for (int reg = 0; reg < 4; reg++) l_run[reg] = 1.0f / l_run[reg];
#pragma unroll
  for (int df = 0; df < 8; df++) {
#pragma unroll
    for (int reg = 0; reg < 4; reg++) {
      int row = q0 + q * 4 + reg;
      int col = h * DH + df * 16 + r;
      of[((size_t)b * T_SZ + row) * DM + col] = f2bf(oacc[df][reg] * l_run[reg]);
    }
  }
}

extern "C" void kernel_launch(void* const* d_in, const int* in_sizes, int n_in,
                              void* d_out, int out_size, void* d_ws, size_t ws_size,
                              hipStream_t stream) {
  (void)in_sizes; (void)n_in; (void)out_size; (void)ws_size;
  const float* x = (const float*)d_in[0];
  const float* w_qkv = (const float*)d_in[1];
  const float* w_out = (const float*)d_in[2];
  float* out = (float*)d_out;

  char* ws = (char*)d_ws;
  size_t off = 0;
  auto alloc = [&](size_t bytes) {
    char* p = ws + off;
    off += (bytes + 255) & ~(size_t)255;
    return p;
  };
  unsigned short* x_bf  = (unsigned short*)alloc((size_t)M_SZ * KD * 2);
  unsigned short* wq_bf = (unsigned short*)alloc((size_t)N1 * KD * 2);
  unsigned short* wo_bf = (unsigned short*)alloc((size_t)DM * KD * 2);
  unsigned short* qkv   = (unsigned short*)alloc((size_t)M_SZ * N1 * 2);
  unsigned short* qb    = (unsigned short*)alloc((size_t)B_SZ * H_SZ * T_SZ * DH * 2);
  unsigned short* kbuf  = (unsigned short*)alloc((size_t)B_SZ * H_SZ * T_SZ * DH * 2);
  unsigned short* vt    = (unsigned short*)alloc((size_t)B_SZ * H_SZ * DH * T_SZ * 2);
  unsigned short* oflat = (unsigned short*)alloc((size_t)M_SZ * DM * 2);
  float* cosb = (float*)alloc((size_t)T_SZ * 64 * 4);
  float* sinb = (float*)alloc((size_t)T_SZ * 64 * 4);

  cast_f32_bf16<<<8192, 256, 0, stream>>>(x, x_bf, M_SZ * KD / 4);
  cast_f32_bf16<<<12288, 256, 0, stream>>>(w_qkv, wq_bf, N1 * KD / 4);
  cast_f32_bf16<<<4096, 256, 0, stream>>>(w_out, wo_bf, DM * KD / 4);
  rope_table<<<T_SZ, 64, 0, stream>>>(cosb, sinb);

  gemm_bt<true><<<dim3(N1 / 128, M_SZ / 128), 256, 0, stream>>>(x_bf, wq_bf, qkv, M_SZ, N1, KD);

  rope_scatter_qk<<<16384, 256, 0, stream>>>(qkv, cosb, sinb, qb, kbuf);
  v_transpose<<<dim3(T_SZ / 32, 4, B_SZ * H_SZ), 256, 0, stream>>>(qkv, vt);

  attn_fwd<<<dim3(T_SZ / 16, B_SZ * H_SZ), 64, 0, stream>>>(qb, kbuf, vt, oflat);

  gemm_bt<false><<<dim3(DM / 128, M_SZ / 128), 256, 0, stream>>>(oflat, wo_bf, out, M_SZ, DM, KD);
}

// Round 3
// 432.743 us; speedup vs baseline: 1.5941x; 1.5941x over previous
//
#include <hip/hip_runtime.h>
#include <hip/hip_bf16.h>

typedef __attribute__((ext_vector_type(4))) float f32x4;
typedef __attribute__((ext_vector_type(8))) short short8;
typedef __attribute__((ext_vector_type(4))) unsigned short ushx4;

#define B_SZ 2
#define T_SZ 2048
#define H_SZ 16
#define DH 128
#define DM 2048
#define M_SZ 4096   // B*T
#define N1 6144     // 3*DM
#define KD 2048

static __device__ __forceinline__ unsigned short f2bf(float f) {
  union { float f; unsigned int u; } v; v.f = f;
  unsigned int r = v.u + 0x7fffu + ((v.u >> 16) & 1u);
  return (unsigned short)(r >> 16);
}
static __device__ __forceinline__ float bf2f(unsigned int u) {
  union { unsigned int u; float f; } v; v.u = u << 16; return v.f;
}

#define ASYNC_COPY16(gsrc, ldst) \
  __builtin_amdgcn_global_load_lds((const __attribute__((address_space(1))) void*)(gsrc), \
                                   (__attribute__((address_space(3))) void*)(ldst), 16, 0, 0)

// ---------------- cast fp32 -> bf16 ----------------
__global__ __launch_bounds__(256) void cast_f32_bf16(const float* __restrict__ in,
                                                     unsigned short* __restrict__ out, int n4) {
  int i = blockIdx.x * 256 + threadIdx.x;
  if (i >= n4) return;
  float4 v = ((const float4*)in)[i];
  ushx4 o;
  o[0] = f2bf(v.x); o[1] = f2bf(v.y); o[2] = f2bf(v.z); o[3] = f2bf(v.w);
  ((ushx4*)out)[i] = o;
}

// ---------------- rope tables ----------------
__global__ __launch_bounds__(64) void rope_table(float* __restrict__ cosb, float* __restrict__ sinb) {
  int t = blockIdx.x;
  int i = threadIdx.x;  // 0..63
  float inv = powf(10000.0f, -(float)i / 64.0f);
  float ang = (float)t * inv;
  cosb[t * 64 + i] = cosf(ang);
  sinb[t * 64 + i] = sinf(ang);
}

// ---------------- GEMM: C[m][n] = sum_k A[m][k] * Bt[n][k]  (both K-major bf16) ----------------
template <bool BF16OUT>
__global__ __launch_bounds__(256) void gemm_bt(const unsigned short* __restrict__ A,
                                               const unsigned short* __restrict__ Bt,
                                               void* __restrict__ Cout,
                                               int M, int N, int K) {
  __shared__ unsigned short As[128 * 32];
  __shared__ unsigned short Bs[128 * 32];
  const int tid = threadIdx.x;
  const int lane = tid & 63;
  const int wave = tid >> 6;
  const int wm = wave >> 1, wn = wave & 1;
  const int m0 = blockIdx.y * 128, n0 = blockIdx.x * 128;
  const int r = lane & 15, q = lane >> 4;

  f32x4 acc[4][4];
#pragma unroll
  for (int i = 0; i < 4; i++)
#pragma unroll
    for (int j = 0; j < 4; j++) acc[i][j] = (f32x4)0.0f;

  const int c0 = tid, c1 = tid + 256;
  const int row0 = c0 >> 2, kc0 = c0 & 3;
  const int row1 = c1 >> 2, kc1 = c1 & 3;

  for (int k0 = 0; k0 < K; k0 += 32) {
    __syncthreads();
    ASYNC_COPY16(A + (size_t)(m0 + row0) * K + k0 + kc0 * 8, &As[c0 * 8]);
    ASYNC_COPY16(A + (size_t)(m0 + row1) * K + k0 + kc1 * 8, &As[c1 * 8]);
    ASYNC_COPY16(Bt + (size_t)(n0 + row0) * K + k0 + kc0 * 8, &Bs[c0 * 8]);
    ASYNC_COPY16(Bt + (size_t)(n0 + row1) * K + k0 + kc1 * 8, &Bs[c1 * 8]);
    __syncthreads();

    short8 a[4], b[4];
#pragma unroll
    for (int mf = 0; mf < 4; mf++)
      a[mf] = *(const short8*)&As[(wm * 64 + mf * 16 + r) * 32 + q * 8];
#pragma unroll
    for (int nf = 0; nf < 4; nf++)
      b[nf] = *(const short8*)&Bs[(wn * 64 + nf * 16 + r) * 32 + q * 8];
#pragma unroll
    for (int mf = 0; mf < 4; mf++)
#pragma unroll
      for (int nf = 0; nf < 4; nf++)
        acc[mf][nf] = __builtin_amdgcn_mfma_f32_16x16x32_bf16(a[mf], b[nf], acc[mf][nf], 0, 0, 0);
  }

#pragma unroll
  for (int mf = 0; mf < 4; mf++) {
#pragma unroll
    for (int nf = 0; nf < 4; nf++) {
#pragma unroll
      for (int reg = 0; reg < 4; reg++) {
        int row = m0 + wm * 64 + mf * 16 + q * 4 + reg;
        int col = n0 + wn * 64 + nf * 16 + r;
        if (BF16OUT)
          ((unsigned short*)Cout)[(size_t)row * N + col] = f2bf(acc[mf][nf][reg]);
        else
          ((float*)Cout)[(size_t)row * N + col] = acc[mf][nf][reg];
      }
    }
  }
}

// ---------------- RoPE + scatter q,k into (B,H,T,DH) ----------------
__global__ __launch_bounds__(256) void rope_scatter_qk(const unsigned short* __restrict__ qkv,
                                                       const float* __restrict__ cosb,
                                                       const float* __restrict__ sinb,
                                                       unsigned short* __restrict__ qb,
                                                       unsigned short* __restrict__ kb) {
  int idx = blockIdx.x * 256 + threadIdx.x;   // 0 .. 4096*1024-1
  int m = idx >> 10;        // row in [0,4096)
  int p = idx & 1023;       // pair index within 2048 cols
  int h = p >> 6, i = p & 63;
  int t = m & (T_SZ - 1);
  int b = m >> 11;
  float c = cosb[t * 64 + i], s = sinb[t * 64 + i];
  size_t dst = (((size_t)(b * H_SZ + h) * T_SZ + t) * DH) + 2 * i;

  // Q
  unsigned int v = *(const unsigned int*)&qkv[(size_t)m * N1 + h * DH + 2 * i];
  float x1 = bf2f(v & 0xffffu), x2 = bf2f(v >> 16);
  float r1 = x1 * c - x2 * s, r2 = x1 * s + x2 * c;
  *(unsigned int*)&qb[dst] = (unsigned int)f2bf(r1) | ((unsigned int)f2bf(r2) << 16);
  // K
  v = *(const unsigned int*)&qkv[(size_t)m * N1 + DM + h * DH + 2 * i];
  x1 = bf2f(v & 0xffffu); x2 = bf2f(v >> 16);
  r1 = x1 * c - x2 * s; r2 = x1 * s + x2 * c;
  *(unsigned int*)&kb[dst] = (unsigned int)f2bf(r1) | ((unsigned int)f2bf(r2) << 16);
}

// ---------------- V transpose into (B,H,DH,T) ----------------
__global__ __launch_bounds__(256) void v_transpose(const unsigned short* __restrict__ qkv,
                                                   unsigned short* __restrict__ vt) {
  __shared__ unsigned short tile[32][34];
  int bh = blockIdx.z, dblk = blockIdx.y, tblk = blockIdx.x;
  int b = bh >> 4, h = bh & 15;
  int tx = threadIdx.x & 31;
  int ty4 = threadIdx.x >> 5;  // 0..7
#pragma unroll
  for (int rr = 0; rr < 4; rr++) {
    int trow = ty4 * 4 + rr;
    int m = b * T_SZ + tblk * 32 + trow;
    tile[trow][tx] = qkv[(size_t)m * N1 + 2 * DM + h * DH + dblk * 32 + tx];
  }
  __syncthreads();
#pragma unroll
  for (int rr = 0; rr < 4; rr++) {
    int drow = ty4 * 4 + rr;
    vt[((size_t)bh * DH + dblk * 32 + drow) * T_SZ + tblk * 32 + tx] = tile[tx][drow];
  }
}

// ---------------- causal flash attention v2 ----------------
// 4 waves/block, QBLK=64 (16 rows/wave), KVBLK=64.
// K double-buffered LDS (prefetch, counted vmcnt), V single-buffered.
// XOR-swizzled LDS (linear dest + inverse-swizzled global src + swizzled ds_read).
// Balanced causal pairing: block handles q-tiles (qi, 31-qi) -> 33 tiles each.
__global__ __launch_bounds__(256) void attn_fwd2(const unsigned short* __restrict__ qb,
                                                 const unsigned short* __restrict__ kb,
                                                 const unsigned short* __restrict__ vt,
                                                 unsigned short* __restrict__ of) {
  __shared__ unsigned short Ks[2][64 * 128];   // 2 x 16 KB
  __shared__ unsigned short Vs[128 * 64];      // 16 KB  (V^T tile: [d][kv])
  __shared__ unsigned short P_lds[4][16 * 72]; // per-wave P

  const int tid = threadIdx.x;
  const int lane = tid & 63;
  const int w = tid >> 6;
  const int r = lane & 15, q = lane >> 4;
  const float scale = 0.08838834764831845f;  // 1/sqrt(128)

  // XCD-aware remap: 16 q-blocks of one (b,h) land on one XCD (K/V L2 reuse).
  int flat = blockIdx.x + 16 * blockIdx.y;   // grid (16, 32) -> 512 blocks
  int xcd = flat & 7;
  int j = flat >> 3;            // 0..63
  int bh = xcd * 4 + (j & 3);   // 0..31
  int qi = j >> 2;              // 0..15

  const int b = bh >> 4, h = bh & 15;
  const unsigned short* __restrict__ Qhead = qb + (size_t)bh * T_SZ * DH;
  const unsigned short* __restrict__ Kbase = kb + (size_t)bh * T_SZ * DH;
  const unsigned short* __restrict__ Vbase = vt + (size_t)bh * DH * T_SZ;

  // stage K tile [64 rows][128 d] -> Ks[buf]; swizzle: chunk' = chunk ^ (row&7)
  auto stageK = [&](int kv0, int buf) {
#pragma unroll
    for (int p = 0; p < 4; p++) {
      int cc = p * 256 + tid;          // 0..1023 chunk id
      int row = cc >> 4, cr = cc & 15; // 16 x 16B chunks per 256B row
      ASYNC_COPY16(Kbase + (size_t)(kv0 + row) * DH + ((cr ^ (row & 7)) * 8),
                   &Ks[buf][cc * 8]);
    }
  };
  // stage V^T tile [128 d-rows][64 kv] -> Vs; swizzle chunk' = chunk ^ (row&7)
  auto stageV = [&](int kv0) {
#pragma unroll
    for (int p = 0; p < 4; p++) {
      int cc = p * 256 + tid;          // 0..1023
      int row = cc >> 3, cr = cc & 7;  // 8 x 16B chunks per 128B row
      ASYNC_COPY16(Vbase + (size_t)row * T_SZ + kv0 + ((cr ^ (row & 7)) * 8),
                   &Vs[cc * 8]);
    }
  };

#pragma unroll 1
  for (int half = 0; half < 2; half++) {
    const int qtile = (half == 0) ? qi : (31 - qi);
    const int q0 = qtile * 64;
    const int qw = q0 + w * 16;       // wave's first q row
    const int nt = qtile + 1;

    int cur = 0;
    stageK(0, 0);

    short8 qf[4];
#pragma unroll
    for (int c = 0; c < 4; c++)
      qf[c] = *(const short8*)(Qhead + (size_t)(qw + r) * DH + c * 32 + q * 8);

    float m_run[4], l_run[4];
    f32x4 oacc[8];
#pragma unroll
    for (int i = 0; i < 4; i++) { m_run[i] = -1e30f; l_run[i] = 0.f; }
#pragma unroll
    for (int i = 0; i < 8; i++) oacc[i] = (f32x4)0.f;

#pragma unroll 1
    for (int t = 0; t < nt; t++) {
      const int kv0 = t * 64;
      stageV(kv0);
      if (t + 1 < nt) {
        stageK(kv0 + 64, cur ^ 1);
        asm volatile("s_waitcnt vmcnt(4)" ::: "memory");  // K(t),V(t) done; K(t+1) in flight
      } else {
        asm volatile("s_waitcnt vmcnt(0)" ::: "memory");
      }
      __builtin_amdgcn_s_barrier();

      // ---- QK^T from Ks[cur] ----
      f32x4 S[4];
#pragma unroll
      for (int nf = 0; nf < 4; nf++) S[nf] = (f32x4)0.f;
#pragma unroll
      for (int nf = 0; nf < 4; nf++) {
#pragma unroll
        for (int c = 0; c < 4; c++) {
          short8 kf = *(const short8*)&Ks[cur][(nf * 16 + r) * 128 + (((c * 4 + q) ^ (r & 7)) * 8)];
          S[nf] = __builtin_amdgcn_mfma_f32_16x16x32_bf16(qf[c], kf, S[nf], 0, 0, 0);
        }
      }

      // ---- mask + scale ----
      float Sv[4][4];
      const bool need_mask = (kv0 + 63 > qw);
#pragma unroll
      for (int nf = 0; nf < 4; nf++) {
#pragma unroll
        for (int reg = 0; reg < 4; reg++) {
          float v = S[nf][reg] * scale;
          if (need_mask) {
            int col = kv0 + nf * 16 + r;
            int row = qw + q * 4 + reg;
            if (col > row) v = -1e30f;
          }
          Sv[nf][reg] = v;
        }
      }

      // ---- online softmax (16-lane reduces, all lanes active) ----
      float pmax[4], sc_old[4], rsum[4];
#pragma unroll
      for (int reg = 0; reg < 4; reg++) {
        float v = fmaxf(fmaxf(Sv[0][reg], Sv[1][reg]), fmaxf(Sv[2][reg], Sv[3][reg]));
#pragma unroll
        for (int s = 1; s < 16; s <<= 1) v = fmaxf(v, __shfl_xor(v, s));
        pmax[reg] = v;
      }
#pragma unroll
      for (int reg = 0; reg < 4; reg++) {
        float mn = fmaxf(m_run[reg], pmax[reg]);
        sc_old[reg] = __expf(m_run[reg] - mn);
        m_run[reg] = mn;
        rsum[reg] = 0.f;
      }
#pragma unroll
      for (int nf = 0; nf < 4; nf++) {
#pragma unroll
        for (int reg = 0; reg < 4; reg++) {
          float p = __expf(Sv[nf][reg] - m_run[reg]);
          rsum[reg] += p;
          P_lds[w][(q * 4 + reg) * 72 + nf * 16 + r] = f2bf(p);
        }
      }
#pragma unroll
      for (int reg = 0; reg < 4; reg++) {
        float v = rsum[reg];
#pragma unroll
        for (int s = 1; s < 16; s <<= 1) v += __shfl_xor(v, s);
        l_run[reg] = l_run[reg] * sc_old[reg] + v;
      }
#pragma unroll
      for (int df = 0; df < 8; df++)
#pragma unroll
        for (int reg = 0; reg < 4; reg++) oacc[df][reg] *= sc_old[reg];

      // ---- PV from Vs ----
      short8 pa[2];
#pragma unroll
      for (int kc = 0; kc < 2; kc++)
        pa[kc] = *(const short8*)&P_lds[w][r * 72 + kc * 32 + q * 8];
#pragma unroll
      for (int df = 0; df < 8; df++) {
#pragma unroll
        for (int kc = 0; kc < 2; kc++) {
          short8 vf = *(const short8*)&Vs[(df * 16 + r) * 64 + (((kc * 4 + q) ^ (r & 7)) * 8)];
          oacc[df] = __builtin_amdgcn_mfma_f32_16x16x32_bf16(pa[kc], vf, oacc[df], 0, 0, 0);
        }
      }

      __builtin_amdgcn_s_barrier();  // all waves done reading Ks[cur]/Vs before overwrite
      cur ^= 1;
    }

    // ---- epilogue ----
#pragma unroll
    for (int reg = 0; reg < 4; reg++) l_run[reg] = 1.0f / l_run[reg];
#pragma unroll
    for (int df = 0; df < 8; df++) {
#pragma unroll
      for (int reg = 0; reg < 4; reg++) {
        int row = qw + q * 4 + reg;
        int col = h * DH + df * 16 + r;
        of[((size_t)b * T_SZ + row) * DM + col] = f2bf(oacc[df][reg] * l_run[reg]);
      }
    }
  }
}

extern "C" void kernel_launch(void* const* d_in, const int* in_sizes, int n_in,
                              void* d_out, int out_size, void* d_ws, size_t ws_size,
                              hipStream_t stream) {
  (void)in_sizes; (void)n_in; (void)out_size; (void)ws_size;
  const float* x = (const float*)d_in[0];
  const float* w_qkv = (const float*)d_in[1];
  const float* w_out = (const float*)d_in[2];
  float* out = (float*)d_out;

  char* ws = (char*)d_ws;
  size_t off = 0;
  auto alloc = [&](size_t bytes) {
    char* p = ws + off;
    off += (bytes + 255) & ~(size_t)255;
    return p;
  };
  unsigned short* x_bf  = (unsigned short*)alloc((size_t)M_SZ * KD * 2);
  unsigned short* wq_bf = (unsigned short*)alloc((size_t)N1 * KD * 2);
  unsigned short* wo_bf = (unsigned short*)alloc((size_t)DM * KD * 2);
  unsigned short* qkv   = (unsigned short*)alloc((size_t)M_SZ * N1 * 2);
  unsigned short* qb    = (unsigned short*)alloc((size_t)B_SZ * H_SZ * T_SZ * DH * 2);
  unsigned short* kbuf  = (unsigned short*)alloc((size_t)B_SZ * H_SZ * T_SZ * DH * 2);
  unsigned short* vt    = (unsigned short*)alloc((size_t)B_SZ * H_SZ * DH * T_SZ * 2);
  unsigned short* oflat = (unsigned short*)alloc((size_t)M_SZ * DM * 2);
  float* cosb = (float*)alloc((size_t)T_SZ * 64 * 4);
  float* sinb = (float*)alloc((size_t)T_SZ * 64 * 4);

  cast_f32_bf16<<<8192, 256, 0, stream>>>(x, x_bf, M_SZ * KD / 4);
  cast_f32_bf16<<<12288, 256, 0, stream>>>(w_qkv, wq_bf, N1 * KD / 4);
  cast_f32_bf16<<<4096, 256, 0, stream>>>(w_out, wo_bf, DM * KD / 4);
  rope_table<<<T_SZ, 64, 0, stream>>>(cosb, sinb);

  gemm_bt<true><<<dim3(N1 / 128, M_SZ / 128), 256, 0, stream>>>(x_bf, wq_bf, qkv, M_SZ, N1, KD);

  rope_scatter_qk<<<16384, 256, 0, stream>>>(qkv, cosb, sinb, qb, kbuf);
  v_transpose<<<dim3(T_SZ / 32, 4, B_SZ * H_SZ), 256, 0, stream>>>(qkv, vt);

  attn_fwd2<<<dim3(16, 32), 256, 0, stream>>>(qb, kbuf, vt, oflat);

  gemm_bt<false><<<dim3(DM / 128, M_SZ / 128), 256, 0, stream>>>(oflat, wo_bf, out, M_SZ, DM, KD);
}

// Round 6
// 413.953 us; speedup vs baseline: 1.6665x; 1.0454x over previous
//
#include <hip/hip_runtime.h>
#include <hip/hip_bf16.h>

typedef __attribute__((ext_vector_type(4))) float f32x4;
typedef __attribute__((ext_vector_type(8))) short short8;
typedef __attribute__((ext_vector_type(4))) unsigned short ushx4;

#define B_SZ 2
#define T_SZ 2048
#define H_SZ 16
#define DH 128
#define DM 2048
#define M_SZ 4096   // B*T
#define N1 6144     // 3*DM
#define KD 2048

static __device__ __forceinline__ unsigned short f2bf(float f) {
  union { float f; unsigned int u; } v; v.f = f;
  unsigned int r = v.u + 0x7fffu + ((v.u >> 16) & 1u);
  return (unsigned short)(r >> 16);
}
static __device__ __forceinline__ float bf2f(unsigned int u) {
  union { unsigned int u; float f; } v; v.u = u << 16; return v.f;
}

#define ASYNC_COPY16(gsrc, ldst) \
  __builtin_amdgcn_global_load_lds((const __attribute__((address_space(1))) void*)(gsrc), \
                                   (__attribute__((address_space(3))) void*)(ldst), 16, 0, 0)

// ---------------- cast fp32 -> bf16 ----------------
__global__ __launch_bounds__(256) void cast_f32_bf16(const float* __restrict__ in,
                                                     unsigned short* __restrict__ out, int n4) {
  int i = blockIdx.x * 256 + threadIdx.x;
  if (i >= n4) return;
  float4 v = ((const float4*)in)[i];
  ushx4 o;
  o[0] = f2bf(v.x); o[1] = f2bf(v.y); o[2] = f2bf(v.z); o[3] = f2bf(v.w);
  ((ushx4*)out)[i] = o;
}

// ---------------- rope tables ----------------
__global__ __launch_bounds__(64) void rope_table(float* __restrict__ cosb, float* __restrict__ sinb) {
  int t = blockIdx.x;
  int i = threadIdx.x;  // 0..63
  float inv = powf(10000.0f, -(float)i / 64.0f);
  float ang = (float)t * inv;
  cosb[t * 64 + i] = cosf(ang);
  sinb[t * 64 + i] = sinf(ang);
}

// ---------------- 8-phase 256-row GEMM: C[m][n] = sum_k A[m][k]*Bt[n][k] ----------------
// BM=256, BN in {256,128}, BK=64 (2 k-halves of 32). 8 waves (2M x 4N).
// LDS: 2-deep ring per (A/B, k-half) slot. 1 half-tile staged per phase.
// Counted vmcnt (never 0 in main loop), setprio around MFMA, XOR bank swizzle.
template <int BN, bool BF16OUT>
__global__ __launch_bounds__(512) void gemm8p(const unsigned short* __restrict__ A,
                                              const unsigned short* __restrict__ Bt,
                                              void* __restrict__ Cout,
                                              int N, int nbx) {
  constexpr int NF = BN / 64;    // n-frags per wave
  constexpr int LB = BN / 128;   // gload_lds per B k-half
  constexpr int NT = KD / 64;    // 32 K-tiles
  constexpr int WCOL = BN / 4;   // wave col span

  __shared__ unsigned short As[2][2][256 * 32];  // [buf][kh][row*32 + swz]
  __shared__ unsigned short Bs[2][2][BN * 32];

  const int tid = threadIdx.x;
  const int lane = tid & 63;
  const int w = tid >> 6;
  const int wm = w >> 2, wn = w & 3;
  const int r = lane & 15, q = lane >> 4;

  // bijective XCD swizzle (gridDim.x % 8 == 0)
  const int cpx = gridDim.x >> 3;
  const int f = (blockIdx.x & 7) * cpx + (blockIdx.x >> 3);
  const int by = f / nbx, bx = f % nbx;
  const int m0 = by * 256, n0 = bx * BN;

  auto stageA = [&](int kt, int kh, int buf) {
#pragma unroll
    for (int l = 0; l < 2; l++) {
      int cc = l * 512 + tid;
      int row = cc >> 2, c = cc & 3;
      ASYNC_COPY16(A + (size_t)(m0 + row) * KD + kt * 64 + kh * 32 + ((c ^ ((row >> 1) & 3)) * 8),
                   &As[buf][kh][cc * 8]);
    }
  };
  auto stageB = [&](int kt, int kh, int buf) {
#pragma unroll
    for (int l = 0; l < LB; l++) {
      int cc = l * 512 + tid;
      int row = cc >> 2, c = cc & 3;
      ASYNC_COPY16(Bt + (size_t)(n0 + row) * KD + kt * 64 + kh * 32 + ((c ^ ((row >> 1) & 3)) * 8),
                   &Bs[buf][kh][cc * 8]);
    }
  };

  f32x4 acc[8][NF];
#pragma unroll
  for (int i = 0; i < 8; i++)
#pragma unroll
    for (int j = 0; j < NF; j++) acc[i][j] = (f32x4)0.0f;

  short8 a[4], b[NF];

  // ---- prologue: stage K-tile 0 fully; wait k-half0 done (k-half1 stays in flight)
  stageA(0, 0, 0); stageB(0, 0, 0); stageA(0, 1, 0); stageB(0, 1, 0);
  if constexpr (BN == 256) asm volatile("s_waitcnt vmcnt(4)" ::: "memory");
  else                     asm volatile("s_waitcnt vmcnt(3)" ::: "memory");
  __builtin_amdgcn_s_barrier();

#pragma unroll 1
  for (int t = 0; t < NT; t++) {
    const int buf = t & 1, nb = buf ^ 1;
    const bool pf = (t + 1 < NT);

    // ---------- phase 1: kk=0, m-half 0 ----------
#pragma unroll
    for (int mf = 0; mf < 4; mf++) {
      int row = wm * 128 + mf * 16 + r;
      a[mf] = *(const short8*)&As[buf][0][row * 32 + ((q ^ ((row >> 1) & 3)) * 8)];
    }
#pragma unroll
    for (int nf = 0; nf < NF; nf++) {
      int row = wn * WCOL + nf * 16 + r;
      b[nf] = *(const short8*)&Bs[buf][0][row * 32 + ((q ^ ((row >> 1) & 3)) * 8)];
    }
    if (pf) stageA(t + 1, 0, nb);
    __builtin_amdgcn_s_barrier();
    __builtin_amdgcn_s_setprio(1);
#pragma unroll
    for (int mf = 0; mf < 4; mf++)
#pragma unroll
      for (int nf = 0; nf < NF; nf++)
        acc[mf][nf] = __builtin_amdgcn_mfma_f32_16x16x32_bf16(a[mf], b[nf], acc[mf][nf], 0, 0, 0);
    __builtin_amdgcn_s_setprio(0);
    __builtin_amdgcn_s_barrier();

    // ---------- phase 2: kk=0, m-half 1 ----------
#pragma unroll
    for (int mf = 0; mf < 4; mf++) {
      int row = wm * 128 + 64 + mf * 16 + r;
      a[mf] = *(const short8*)&As[buf][0][row * 32 + ((q ^ ((row >> 1) & 3)) * 8)];
    }
    if (pf) {
      stageB(t + 1, 0, nb);
      if constexpr (BN == 256) asm volatile("s_waitcnt vmcnt(4)" ::: "memory");
      else                     asm volatile("s_waitcnt vmcnt(3)" ::: "memory");
    } else {
      asm volatile("s_waitcnt vmcnt(0)" ::: "memory");
    }
    __builtin_amdgcn_s_barrier();
    __builtin_amdgcn_s_setprio(1);
#pragma unroll
    for (int mf = 0; mf < 4; mf++)
#pragma unroll
      for (int nf = 0; nf < NF; nf++)
        acc[4 + mf][nf] = __builtin_amdgcn_mfma_f32_16x16x32_bf16(a[mf], b[nf], acc[4 + mf][nf], 0, 0, 0);
    __builtin_amdgcn_s_setprio(0);
    __builtin_amdgcn_s_barrier();

    // ---------- phase 3: kk=1, m-half 0 ----------
#pragma unroll
    for (int mf = 0; mf < 4; mf++) {
      int row = wm * 128 + mf * 16 + r;
      a[mf] = *(const short8*)&As[buf][1][row * 32 + ((q ^ ((row >> 1) & 3)) * 8)];
    }
#pragma unroll
    for (int nf = 0; nf < NF; nf++) {
      int row = wn * WCOL + nf * 16 + r;
      b[nf] = *(const short8*)&Bs[buf][1][row * 32 + ((q ^ ((row >> 1) & 3)) * 8)];
    }
    if (pf) stageA(t + 1, 1, nb);
    __builtin_amdgcn_s_barrier();
    __builtin_amdgcn_s_setprio(1);
#pragma unroll
    for (int mf = 0; mf < 4; mf++)
#pragma unroll
      for (int nf = 0; nf < NF; nf++)
        acc[mf][nf] = __builtin_amdgcn_mfma_f32_16x16x32_bf16(a[mf], b[nf], acc[mf][nf], 0, 0, 0);
    __builtin_amdgcn_s_setprio(0);
    __builtin_amdgcn_s_barrier();

    // ---------- phase 4: kk=1, m-half 1 ----------
#pragma unroll
    for (int mf = 0; mf < 4; mf++) {
      int row = wm * 128 + 64 + mf * 16 + r;
      a[mf] = *(const short8*)&As[buf][1][row * 32 + ((q ^ ((row >> 1) & 3)) * 8)];
    }
    if (pf) {
      stageB(t + 1, 1, nb);
      if constexpr (BN == 256) asm volatile("s_waitcnt vmcnt(4)" ::: "memory");
      else                     asm volatile("s_waitcnt vmcnt(3)" ::: "memory");
    } else {
      asm volatile("s_waitcnt vmcnt(0)" ::: "memory");
    }
    __builtin_amdgcn_s_barrier();
    __builtin_amdgcn_s_setprio(1);
#pragma unroll
    for (int mf = 0; mf < 4; mf++)
#pragma unroll
      for (int nf = 0; nf < NF; nf++)
        acc[4 + mf][nf] = __builtin_amdgcn_mfma_f32_16x16x32_bf16(a[mf], b[nf], acc[4 + mf][nf], 0, 0, 0);
    __builtin_amdgcn_s_setprio(0);
    __builtin_amdgcn_s_barrier();
  }

  // ---- epilogue ----
#pragma unroll
  for (int mf = 0; mf < 8; mf++) {
#pragma unroll
    for (int nf = 0; nf < NF; nf++) {
#pragma unroll
      for (int reg = 0; reg < 4; reg++) {
        int row = m0 + wm * 128 + mf * 16 + q * 4 + reg;
        int col = n0 + wn * WCOL + nf * 16 + r;
        if (BF16OUT)
          ((unsigned short*)Cout)[(size_t)row * N + col] = f2bf(acc[mf][nf][reg]);
        else
          ((float*)Cout)[(size_t)row * N + col] = acc[mf][nf][reg];
      }
    }
  }
}

// ---------------- RoPE + scatter q,k into (B,H,T,DH) ----------------
__global__ __launch_bounds__(256) void rope_scatter_qk(const unsigned short* __restrict__ qkv,
                                                       const float* __restrict__ cosb,
                                                       const float* __restrict__ sinb,
                                                       unsigned short* __restrict__ qb,
                                                       unsigned short* __restrict__ kb) {
  int idx = blockIdx.x * 256 + threadIdx.x;   // 0 .. 4096*1024-1
  int m = idx >> 10;        // row in [0,4096)
  int p = idx & 1023;       // pair index within 2048 cols
  int h = p >> 6, i = p & 63;
  int t = m & (T_SZ - 1);
  int b = m >> 11;
  float c = cosb[t * 64 + i], s = sinb[t * 64 + i];
  size_t dst = (((size_t)(b * H_SZ + h) * T_SZ + t) * DH) + 2 * i;

  // Q
  unsigned int v = *(const unsigned int*)&qkv[(size_t)m * N1 + h * DH + 2 * i];
  float x1 = bf2f(v & 0xffffu), x2 = bf2f(v >> 16);
  float r1 = x1 * c - x2 * s, r2 = x1 * s + x2 * c;
  *(unsigned int*)&qb[dst] = (unsigned int)f2bf(r1) | ((unsigned int)f2bf(r2) << 16);
  // K
  v = *(const unsigned int*)&qkv[(size_t)m * N1 + DM + h * DH + 2 * i];
  x1 = bf2f(v & 0xffffu); x2 = bf2f(v >> 16);
  r1 = x1 * c - x2 * s; r2 = x1 * s + x2 * c;
  *(unsigned int*)&kb[dst] = (unsigned int)f2bf(r1) | ((unsigned int)f2bf(r2) << 16);
}

// ---------------- V transpose into (B,H,DH,T) ----------------
__global__ __launch_bounds__(256) void v_transpose(const unsigned short* __restrict__ qkv,
                                                   unsigned short* __restrict__ vt) {
  __shared__ unsigned short tile[32][34];
  int bh = blockIdx.z, dblk = blockIdx.y, tblk = blockIdx.x;
  int b = bh >> 4, h = bh & 15;
  int tx = threadIdx.x & 31;
  int ty4 = threadIdx.x >> 5;  // 0..7
#pragma unroll
  for (int rr = 0; rr < 4; rr++) {
    int trow = ty4 * 4 + rr;
    int m = b * T_SZ + tblk * 32 + trow;
    tile[trow][tx] = qkv[(size_t)m * N1 + 2 * DM + h * DH + dblk * 32 + tx];
  }
  __syncthreads();
#pragma unroll
  for (int rr = 0; rr < 4; rr++) {
    int drow = ty4 * 4 + rr;
    vt[((size_t)bh * DH + dblk * 32 + drow) * T_SZ + tblk * 32 + tx] = tile[tx][drow];
  }
}

// ---------------- causal flash attention v2 ----------------
__global__ __launch_bounds__(256) void attn_fwd2(const unsigned short* __restrict__ qb,
                                                 const unsigned short* __restrict__ kb,
                                                 const unsigned short* __restrict__ vt,
                                                 unsigned short* __restrict__ of) {
  __shared__ unsigned short Ks[2][64 * 128];   // 2 x 16 KB
  __shared__ unsigned short Vs[128 * 64];      // 16 KB  (V^T tile: [d][kv])
  __shared__ unsigned short P_lds[4][16 * 72]; // per-wave P

  const int tid = threadIdx.x;
  const int lane = tid & 63;
  const int w = tid >> 6;
  const int r = lane & 15, q = lane >> 4;
  const float scale = 0.08838834764831845f;  // 1/sqrt(128)

  int flat = blockIdx.x + 16 * blockIdx.y;   // grid (16, 32) -> 512 blocks
  int xcd = flat & 7;
  int j = flat >> 3;            // 0..63
  int bh = xcd * 4 + (j & 3);   // 0..31
  int qi = j >> 2;              // 0..15

  const int b = bh >> 4, h = bh & 15;
  const unsigned short* __restrict__ Qhead = qb + (size_t)bh * T_SZ * DH;
  const unsigned short* __restrict__ Kbase = kb + (size_t)bh * T_SZ * DH;
  const unsigned short* __restrict__ Vbase = vt + (size_t)bh * DH * T_SZ;

  auto stageK = [&](int kv0, int buf) {
#pragma unroll
    for (int p = 0; p < 4; p++) {
      int cc = p * 256 + tid;          // 0..1023 chunk id
      int row = cc >> 4, cr = cc & 15; // 16 x 16B chunks per 256B row
      ASYNC_COPY16(Kbase + (size_t)(kv0 + row) * DH + ((cr ^ (row & 7)) * 8),
                   &Ks[buf][cc * 8]);
    }
  };
  auto stageV = [&](int kv0) {
#pragma unroll
    for (int p = 0; p < 4; p++) {
      int cc = p * 256 + tid;          // 0..1023
      int row = cc >> 3, cr = cc & 7;  // 8 x 16B chunks per 128B row
      ASYNC_COPY16(Vbase + (size_t)row * T_SZ + kv0 + ((cr ^ (row & 7)) * 8),
                   &Vs[cc * 8]);
    }
  };

#pragma unroll 1
  for (int half = 0; half < 2; half++) {
    const int qtile = (half == 0) ? qi : (31 - qi);
    const int q0 = qtile * 64;
    const int qw = q0 + w * 16;       // wave's first q row
    const int nt = qtile + 1;

    int cur = 0;
    stageK(0, 0);

    short8 qf[4];
#pragma unroll
    for (int c = 0; c < 4; c++)
      qf[c] = *(const short8*)(Qhead + (size_t)(qw + r) * DH + c * 32 + q * 8);

    float m_run[4], l_run[4];
    f32x4 oacc[8];
#pragma unroll
    for (int i = 0; i < 4; i++) { m_run[i] = -1e30f; l_run[i] = 0.f; }
#pragma unroll
    for (int i = 0; i < 8; i++) oacc[i] = (f32x4)0.f;

#pragma unroll 1
    for (int t = 0; t < nt; t++) {
      const int kv0 = t * 64;
      stageV(kv0);
      if (t + 1 < nt) {
        stageK(kv0 + 64, cur ^ 1);
        asm volatile("s_waitcnt vmcnt(4)" ::: "memory");
      } else {
        asm volatile("s_waitcnt vmcnt(0)" ::: "memory");
      }
      __builtin_amdgcn_s_barrier();

      // ---- QK^T from Ks[cur] ----
      f32x4 S[4];
#pragma unroll
      for (int nf = 0; nf < 4; nf++) S[nf] = (f32x4)0.f;
#pragma unroll
      for (int nf = 0; nf < 4; nf++) {
#pragma unroll
        for (int c = 0; c < 4; c++) {
          short8 kf = *(const short8*)&Ks[cur][(nf * 16 + r) * 128 + (((c * 4 + q) ^ (r & 7)) * 8)];
          S[nf] = __builtin_amdgcn_mfma_f32_16x16x32_bf16(qf[c], kf, S[nf], 0, 0, 0);
        }
      }

      float Sv[4][4];
      const bool need_mask = (kv0 + 63 > qw);
#pragma unroll
      for (int nf = 0; nf < 4; nf++) {
#pragma unroll
        for (int reg = 0; reg < 4; reg++) {
          float v = S[nf][reg] * scale;
          if (need_mask) {
            int col = kv0 + nf * 16 + r;
            int row = qw + q * 4 + reg;
            if (col > row) v = -1e30f;
          }
          Sv[nf][reg] = v;
        }
      }

      float pmax[4], sc_old[4], rsum[4];
#pragma unroll
      for (int reg = 0; reg < 4; reg++) {
        float v = fmaxf(fmaxf(Sv[0][reg], Sv[1][reg]), fmaxf(Sv[2][reg], Sv[3][reg]));
#pragma unroll
        for (int s = 1; s < 16; s <<= 1) v = fmaxf(v, __shfl_xor(v, s));
        pmax[reg] = v;
      }
#pragma unroll
      for (int reg = 0; reg < 4; reg++) {
        float mn = fmaxf(m_run[reg], pmax[reg]);
        sc_old[reg] = __expf(m_run[reg] - mn);
        m_run[reg] = mn;
        rsum[reg] = 0.f;
      }
#pragma unroll
      for (int nf = 0; nf < 4; nf++) {
#pragma unroll
        for (int reg = 0; reg < 4; reg++) {
          float p = __expf(Sv[nf][reg] - m_run[reg]);
          rsum[reg] += p;
          P_lds[w][(q * 4 + reg) * 72 + nf * 16 + r] = f2bf(p);
        }
      }
#pragma unroll
      for (int reg = 0; reg < 4; reg++) {
        float v = rsum[reg];
#pragma unroll
        for (int s = 1; s < 16; s <<= 1) v += __shfl_xor(v, s);
        l_run[reg] = l_run[reg] * sc_old[reg] + v;
      }
#pragma unroll
      for (int df = 0; df < 8; df++)
#pragma unroll
        for (int reg = 0; reg < 4; reg++) oacc[df][reg] *= sc_old[reg];

      short8 pa[2];
#pragma unroll
      for (int kc = 0; kc < 2; kc++)
        pa[kc] = *(const short8*)&P_lds[w][r * 72 + kc * 32 + q * 8];
#pragma unroll
      for (int df = 0; df < 8; df++) {
#pragma unroll
        for (int kc = 0; kc < 2; kc++) {
          short8 vf = *(const short8*)&Vs[(df * 16 + r) * 64 + (((kc * 4 + q) ^ (r & 7)) * 8)];
          oacc[df] = __builtin_amdgcn_mfma_f32_16x16x32_bf16(pa[kc], vf, oacc[df], 0, 0, 0);
        }
      }

      __builtin_amdgcn_s_barrier();
      cur ^= 1;
    }

#pragma unroll
    for (int reg = 0; reg < 4; reg++) l_run[reg] = 1.0f / l_run[reg];
#pragma unroll
    for (int df = 0; df < 8; df++) {
#pragma unroll
      for (int reg = 0; reg < 4; reg++) {
        int row = qw + q * 4 + reg;
        int col = h * DH + df * 16 + r;
        of[((size_t)b * T_SZ + row) * DM + col] = f2bf(oacc[df][reg] * l_run[reg]);
      }
    }
  }
}

extern "C" void kernel_launch(void* const* d_in, const int* in_sizes, int n_in,
                              void* d_out, int out_size, void* d_ws, size_t ws_size,
                              hipStream_t stream) {
  (void)in_sizes; (void)n_in; (void)out_size; (void)ws_size;
  const float* x = (const float*)d_in[0];
  const float* w_qkv = (const float*)d_in[1];
  const float* w_out = (const float*)d_in[2];
  float* out = (float*)d_out;

  char* ws = (char*)d_ws;
  size_t off = 0;
  auto alloc = [&](size_t bytes) {
    char* p = ws + off;
    off += (bytes + 255) & ~(size_t)255;
    return p;
  };
  unsigned short* x_bf  = (unsigned short*)alloc((size_t)M_SZ * KD * 2);
  unsigned short* wq_bf = (unsigned short*)alloc((size_t)N1 * KD * 2);
  unsigned short* wo_bf = (unsigned short*)alloc((size_t)DM * KD * 2);
  unsigned short* qkv   = (unsigned short*)alloc((size_t)M_SZ * N1 * 2);
  unsigned short* qb    = (unsigned short*)alloc((size_t)B_SZ * H_SZ * T_SZ * DH * 2);
  unsigned short* kbuf  = (unsigned short*)alloc((size_t)B_SZ * H_SZ * T_SZ * DH * 2);
  unsigned short* vt    = (unsigned short*)alloc((size_t)B_SZ * H_SZ * DH * T_SZ * 2);
  unsigned short* oflat = (unsigned short*)alloc((size_t)M_SZ * DM * 2);
  float* cosb = (float*)alloc((size_t)T_SZ * 64 * 4);
  float* sinb = (float*)alloc((size_t)T_SZ * 64 * 4);

  cast_f32_bf16<<<8192, 256, 0, stream>>>(x, x_bf, M_SZ * KD / 4);
  cast_f32_bf16<<<12288, 256, 0, stream>>>(w_qkv, wq_bf, N1 * KD / 4);
  cast_f32_bf16<<<4096, 256, 0, stream>>>(w_out, wo_bf, DM * KD / 4);
  rope_table<<<T_SZ, 64, 0, stream>>>(cosb, sinb);

  // QKV projection: M=4096, N=6144 -> 16 x 24 = 384 blocks (384 % 8 == 0)
  gemm8p<256, true><<<384, 512, 0, stream>>>(x_bf, wq_bf, qkv, N1, N1 / 256);

  rope_scatter_qk<<<16384, 256, 0, stream>>>(qkv, cosb, sinb, qb, kbuf);
  v_transpose<<<dim3(T_SZ / 32, 4, B_SZ * H_SZ), 256, 0, stream>>>(qkv, vt);

  attn_fwd2<<<dim3(16, 32), 256, 0, stream>>>(qb, kbuf, vt, oflat);

  // out projection: M=4096, N=2048, BN=128 -> 16 x 16 = 256 blocks (1/CU exact)
  gemm8p<128, false><<<256, 512, 0, stream>>>(oflat, wo_bf, out, DM, DM / 128);
}

// Round 7
// 402.822 us; speedup vs baseline: 1.7126x; 1.0276x over previous
//
#include <hip/hip_runtime.h>
#include <hip/hip_bf16.h>

typedef __attribute__((ext_vector_type(4))) float f32x4;
typedef __attribute__((ext_vector_type(8))) short short8;
typedef __attribute__((ext_vector_type(4))) unsigned short ushx4;

#define B_SZ 2
#define T_SZ 2048
#define H_SZ 16
#define DH 128
#define DM 2048
#define M_SZ 4096   // B*T
#define N1 6144     // 3*DM
#define KD 2048

static __device__ __forceinline__ unsigned short f2bf(float f) {
  union { float f; unsigned int u; } v; v.f = f;
  unsigned int r = v.u + 0x7fffu + ((v.u >> 16) & 1u);
  return (unsigned short)(r >> 16);
}
static __device__ __forceinline__ float bf2f(unsigned int u) {
  union { unsigned int u; float f; } v; v.u = u << 16; return v.f;
}

#define ASYNC_COPY16(gsrc, ldst) \
  __builtin_amdgcn_global_load_lds((const __attribute__((address_space(1))) void*)(gsrc), \
                                   (__attribute__((address_space(3))) void*)(ldst), 16, 0, 0)

// ---------------- cast fp32 -> bf16 ----------------
__global__ __launch_bounds__(256) void cast_f32_bf16(const float* __restrict__ in,
                                                     unsigned short* __restrict__ out, int n4) {
  int i = blockIdx.x * 256 + threadIdx.x;
  if (i >= n4) return;
  float4 v = ((const float4*)in)[i];
  ushx4 o;
  o[0] = f2bf(v.x); o[1] = f2bf(v.y); o[2] = f2bf(v.z); o[3] = f2bf(v.w);
  ((ushx4*)out)[i] = o;
}

// ---------------- rope tables ----------------
__global__ __launch_bounds__(64) void rope_table(float* __restrict__ cosb, float* __restrict__ sinb) {
  int t = blockIdx.x;
  int i = threadIdx.x;  // 0..63
  float inv = powf(10000.0f, -(float)i / 64.0f);
  float ang = (float)t * inv;
  cosb[t * 64 + i] = cosf(ang);
  sinb[t * 64 + i] = sinf(ang);
}

// ---------------- GEMM v3: C[m][n] = sum_k A[m][k]*Bt[n][k] (K-major bf16) ----------------
// BK=32, double-buffered LDS (64 KiB @BM=BN=256 -> 2 blocks/CU; 48 KiB @BM=128 -> 3/CU).
// ONE __syncthreads per K-tile (its implicit vmcnt(0) is exactly the wait for the
// tile staged one iteration earlier); no intra-tile barriers so compiler-scheduled
// lgkmcnt interleaves ds_read under MFMA. XOR bank swizzle on stage-src + read.
template <int BM, int BN, bool BF16OUT>
__global__ __launch_bounds__(512) void gemmv(const unsigned short* __restrict__ A,
                                             const unsigned short* __restrict__ Bt,
                                             void* __restrict__ Cout,
                                             int N, int nbx) {
  constexpr int NF = BN / 64;    // n-frags per wave
  constexpr int MF = BM / 32;    // m-frags per wave
  constexpr int LA = BM / 128;   // gload_lds rounds for A tile
  constexpr int LB = BN / 128;   // gload_lds rounds for B tile
  constexpr int NT = KD / 32;    // 64 K-tiles

  __shared__ unsigned short As[2][BM * 32];
  __shared__ unsigned short Bs[2][BN * 32];

  const int tid = threadIdx.x;
  const int lane = tid & 63;
  const int w = tid >> 6;
  const int wm = w >> 2, wn = w & 3;   // 2 x 4 waves
  const int r = lane & 15, q = lane >> 4;

  // bijective XCD swizzle (gridDim.x % 8 == 0)
  const int cpx = gridDim.x >> 3;
  const int f = (blockIdx.x & 7) * cpx + (blockIdx.x >> 3);
  const int by = f / nbx, bx = f % nbx;
  const int m0 = by * BM, n0 = bx * BN;

  auto stage = [&](int kt, int buf) {
#pragma unroll
    for (int l = 0; l < LA; l++) {
      int cc = l * 512 + tid;
      int row = cc >> 2, c = cc & 3;   // 4 x 16B chunks per 64B row
      ASYNC_COPY16(A + (size_t)(m0 + row) * KD + kt * 32 + ((c ^ ((row >> 1) & 3)) * 8),
                   &As[buf][cc * 8]);
    }
#pragma unroll
    for (int l = 0; l < LB; l++) {
      int cc = l * 512 + tid;
      int row = cc >> 2, c = cc & 3;
      ASYNC_COPY16(Bt + (size_t)(n0 + row) * KD + kt * 32 + ((c ^ ((row >> 1) & 3)) * 8),
                   &Bs[buf][cc * 8]);
    }
  };

  f32x4 acc[MF][NF];
#pragma unroll
  for (int i = 0; i < MF; i++)
#pragma unroll
    for (int j = 0; j < NF; j++) acc[i][j] = (f32x4)0.0f;

  stage(0, 0);

#pragma unroll 1
  for (int t = 0; t < NT; t++) {
    const int buf = t & 1;
    __syncthreads();   // implicit vmcnt(0): tile t's stage has landed for all waves

    short8 a[MF], b[NF];
#pragma unroll
    for (int mf = 0; mf < MF; mf++) {
      int row = wm * (BM / 2) + mf * 16 + r;
      a[mf] = *(const short8*)&As[buf][row * 32 + ((q ^ ((row >> 1) & 3)) * 8)];
    }
#pragma unroll
    for (int nf = 0; nf < NF; nf++) {
      int row = wn * (BN / 4) + nf * 16 + r;
      b[nf] = *(const short8*)&Bs[buf][row * 32 + ((q ^ ((row >> 1) & 3)) * 8)];
    }
    if (t + 1 < NT) stage(t + 1, buf ^ 1);   // in flight across the MFMA cluster

    __builtin_amdgcn_s_setprio(1);
#pragma unroll
    for (int mf = 0; mf < MF; mf++)
#pragma unroll
      for (int nf = 0; nf < NF; nf++)
        acc[mf][nf] = __builtin_amdgcn_mfma_f32_16x16x32_bf16(a[mf], b[nf], acc[mf][nf], 0, 0, 0);
    __builtin_amdgcn_s_setprio(0);
  }

  // ---- epilogue ----
#pragma unroll
  for (int mf = 0; mf < MF; mf++) {
#pragma unroll
    for (int nf = 0; nf < NF; nf++) {
#pragma unroll
      for (int reg = 0; reg < 4; reg++) {
        int row = m0 + wm * (BM / 2) + mf * 16 + q * 4 + reg;
        int col = n0 + wn * (BN / 4) + nf * 16 + r;
        if (BF16OUT)
          ((unsigned short*)Cout)[(size_t)row * N + col] = f2bf(acc[mf][nf][reg]);
        else
          ((float*)Cout)[(size_t)row * N + col] = acc[mf][nf][reg];
      }
    }
  }
}

// ---------------- RoPE + scatter q,k into (B,H,T,DH) ----------------
__global__ __launch_bounds__(256) void rope_scatter_qk(const unsigned short* __restrict__ qkv,
                                                       const float* __restrict__ cosb,
                                                       const float* __restrict__ sinb,
                                                       unsigned short* __restrict__ qb,
                                                       unsigned short* __restrict__ kb) {
  int idx = blockIdx.x * 256 + threadIdx.x;   // 0 .. 4096*1024-1
  int m = idx >> 10;        // row in [0,4096)
  int p = idx & 1023;       // pair index within 2048 cols
  int h = p >> 6, i = p & 63;
  int t = m & (T_SZ - 1);
  int b = m >> 11;
  float c = cosb[t * 64 + i], s = sinb[t * 64 + i];
  size_t dst = (((size_t)(b * H_SZ + h) * T_SZ + t) * DH) + 2 * i;

  // Q
  unsigned int v = *(const unsigned int*)&qkv[(size_t)m * N1 + h * DH + 2 * i];
  float x1 = bf2f(v & 0xffffu), x2 = bf2f(v >> 16);
  float r1 = x1 * c - x2 * s, r2 = x1 * s + x2 * c;
  *(unsigned int*)&qb[dst] = (unsigned int)f2bf(r1) | ((unsigned int)f2bf(r2) << 16);
  // K
  v = *(const unsigned int*)&qkv[(size_t)m * N1 + DM + h * DH + 2 * i];
  x1 = bf2f(v & 0xffffu); x2 = bf2f(v >> 16);
  r1 = x1 * c - x2 * s; r2 = x1 * s + x2 * c;
  *(unsigned int*)&kb[dst] = (unsigned int)f2bf(r1) | ((unsigned int)f2bf(r2) << 16);
}

// ---------------- V transpose into (B,H,DH,T) ----------------
__global__ __launch_bounds__(256) void v_transpose(const unsigned short* __restrict__ qkv,
                                                   unsigned short* __restrict__ vt) {
  __shared__ unsigned short tile[32][34];
  int bh = blockIdx.z, dblk = blockIdx.y, tblk = blockIdx.x;
  int b = bh >> 4, h = bh & 15;
  int tx = threadIdx.x & 31;
  int ty4 = threadIdx.x >> 5;  // 0..7
#pragma unroll
  for (int rr = 0; rr < 4; rr++) {
    int trow = ty4 * 4 + rr;
    int m = b * T_SZ + tblk * 32 + trow;
    tile[trow][tx] = qkv[(size_t)m * N1 + 2 * DM + h * DH + dblk * 32 + tx];
  }
  __syncthreads();
#pragma unroll
  for (int rr = 0; rr < 4; rr++) {
    int drow = ty4 * 4 + rr;
    vt[((size_t)bh * DH + dblk * 32 + drow) * T_SZ + tblk * 32 + tx] = tile[tx][drow];
  }
}

// ---------------- causal flash attention v2 ----------------
__global__ __launch_bounds__(256) void attn_fwd2(const unsigned short* __restrict__ qb,
                                                 const unsigned short* __restrict__ kb,
                                                 const unsigned short* __restrict__ vt,
                                                 unsigned short* __restrict__ of) {
  __shared__ unsigned short Ks[2][64 * 128];   // 2 x 16 KB
  __shared__ unsigned short Vs[128 * 64];      // 16 KB  (V^T tile: [d][kv])
  __shared__ unsigned short P_lds[4][16 * 72]; // per-wave P

  const int tid = threadIdx.x;
  const int lane = tid & 63;
  const int w = tid >> 6;
  const int r = lane & 15, q = lane >> 4;
  const float scale = 0.08838834764831845f;  // 1/sqrt(128)

  int flat = blockIdx.x + 16 * blockIdx.y;   // grid (16, 32) -> 512 blocks
  int xcd = flat & 7;
  int j = flat >> 3;            // 0..63
  int bh = xcd * 4 + (j & 3);   // 0..31
  int qi = j >> 2;              // 0..15

  const int b = bh >> 4, h = bh & 15;
  const unsigned short* __restrict__ Qhead = qb + (size_t)bh * T_SZ * DH;
  const unsigned short* __restrict__ Kbase = kb + (size_t)bh * T_SZ * DH;
  const unsigned short* __restrict__ Vbase = vt + (size_t)bh * DH * T_SZ;

  auto stageK = [&](int kv0, int buf) {
#pragma unroll
    for (int p = 0; p < 4; p++) {
      int cc = p * 256 + tid;          // 0..1023 chunk id
      int row = cc >> 4, cr = cc & 15; // 16 x 16B chunks per 256B row
      ASYNC_COPY16(Kbase + (size_t)(kv0 + row) * DH + ((cr ^ (row & 7)) * 8),
                   &Ks[buf][cc * 8]);
    }
  };
  auto stageV = [&](int kv0) {
#pragma unroll
    for (int p = 0; p < 4; p++) {
      int cc = p * 256 + tid;          // 0..1023
      int row = cc >> 3, cr = cc & 7;  // 8 x 16B chunks per 128B row
      ASYNC_COPY16(Vbase + (size_t)row * T_SZ + kv0 + ((cr ^ (row & 7)) * 8),
                   &Vs[cc * 8]);
    }
  };

#pragma unroll 1
  for (int half = 0; half < 2; half++) {
    const int qtile = (half == 0) ? qi : (31 - qi);
    const int q0 = qtile * 64;
    const int qw = q0 + w * 16;       // wave's first q row
    const int nt = qtile + 1;

    int cur = 0;
    stageK(0, 0);

    short8 qf[4];
#pragma unroll
    for (int c = 0; c < 4; c++)
      qf[c] = *(const short8*)(Qhead + (size_t)(qw + r) * DH + c * 32 + q * 8);

    float m_run[4], l_run[4];
    f32x4 oacc[8];
#pragma unroll
    for (int i = 0; i < 4; i++) { m_run[i] = -1e30f; l_run[i] = 0.f; }
#pragma unroll
    for (int i = 0; i < 8; i++) oacc[i] = (f32x4)0.f;

#pragma unroll 1
    for (int t = 0; t < nt; t++) {
      const int kv0 = t * 64;
      stageV(kv0);
      if (t + 1 < nt) {
        stageK(kv0 + 64, cur ^ 1);
        asm volatile("s_waitcnt vmcnt(4)" ::: "memory");
      } else {
        asm volatile("s_waitcnt vmcnt(0)" ::: "memory");
      }
      __builtin_amdgcn_s_barrier();

      // ---- QK^T from Ks[cur] ----
      f32x4 S[4];
#pragma unroll
      for (int nf = 0; nf < 4; nf++) S[nf] = (f32x4)0.f;
#pragma unroll
      for (int nf = 0; nf < 4; nf++) {
#pragma unroll
        for (int c = 0; c < 4; c++) {
          short8 kf = *(const short8*)&Ks[cur][(nf * 16 + r) * 128 + (((c * 4 + q) ^ (r & 7)) * 8)];
          S[nf] = __builtin_amdgcn_mfma_f32_16x16x32_bf16(qf[c], kf, S[nf], 0, 0, 0);
        }
      }

      float Sv[4][4];
      const bool need_mask = (kv0 + 63 > qw);
#pragma unroll
      for (int nf = 0; nf < 4; nf++) {
#pragma unroll
        for (int reg = 0; reg < 4; reg++) {
          float v = S[nf][reg] * scale;
          if (need_mask) {
            int col = kv0 + nf * 16 + r;
            int row = qw + q * 4 + reg;
            if (col > row) v = -1e30f;
          }
          Sv[nf][reg] = v;
        }
      }

      float pmax[4], sc_old[4], rsum[4];
#pragma unroll
      for (int reg = 0; reg < 4; reg++) {
        float v = fmaxf(fmaxf(Sv[0][reg], Sv[1][reg]), fmaxf(Sv[2][reg], Sv[3][reg]));
#pragma unroll
        for (int s = 1; s < 16; s <<= 1) v = fmaxf(v, __shfl_xor(v, s));
        pmax[reg] = v;
      }
#pragma unroll
      for (int reg = 0; reg < 4; reg++) {
        float mn = fmaxf(m_run[reg], pmax[reg]);
        sc_old[reg] = __expf(m_run[reg] - mn);
        m_run[reg] = mn;
        rsum[reg] = 0.f;
      }
#pragma unroll
      for (int nf = 0; nf < 4; nf++) {
#pragma unroll
        for (int reg = 0; reg < 4; reg++) {
          float p = __expf(Sv[nf][reg] - m_run[reg]);
          rsum[reg] += p;
          P_lds[w][(q * 4 + reg) * 72 + nf * 16 + r] = f2bf(p);
        }
      }
#pragma unroll
      for (int reg = 0; reg < 4; reg++) {
        float v = rsum[reg];
#pragma unroll
        for (int s = 1; s < 16; s <<= 1) v += __shfl_xor(v, s);
        l_run[reg] = l_run[reg] * sc_old[reg] + v;
      }
#pragma unroll
      for (int df = 0; df < 8; df++)
#pragma unroll
        for (int reg = 0; reg < 4; reg++) oacc[df][reg] *= sc_old[reg];

      short8 pa[2];
#pragma unroll
      for (int kc = 0; kc < 2; kc++)
        pa[kc] = *(const short8*)&P_lds[w][r * 72 + kc * 32 + q * 8];
#pragma unroll
      for (int df = 0; df < 8; df++) {
#pragma unroll
        for (int kc = 0; kc < 2; kc++) {
          short8 vf = *(const short8*)&Vs[(df * 16 + r) * 64 + (((kc * 4 + q) ^ (r & 7)) * 8)];
          oacc[df] = __builtin_amdgcn_mfma_f32_16x16x32_bf16(pa[kc], vf, oacc[df], 0, 0, 0);
        }
      }

      __builtin_amdgcn_s_barrier();
      cur ^= 1;
    }

#pragma unroll
    for (int reg = 0; reg < 4; reg++) l_run[reg] = 1.0f / l_run[reg];
#pragma unroll
    for (int df = 0; df < 8; df++) {
#pragma unroll
      for (int reg = 0; reg < 4; reg++) {
        int row = qw + q * 4 + reg;
        int col = h * DH + df * 16 + r;
        of[((size_t)b * T_SZ + row) * DM + col] = f2bf(oacc[df][reg] * l_run[reg]);
      }
    }
  }
}

extern "C" void kernel_launch(void* const* d_in, const int* in_sizes, int n_in,
                              void* d_out, int out_size, void* d_ws, size_t ws_size,
                              hipStream_t stream) {
  (void)in_sizes; (void)n_in; (void)out_size; (void)ws_size;
  const float* x = (const float*)d_in[0];
  const float* w_qkv = (const float*)d_in[1];
  const float* w_out = (const float*)d_in[2];
  float* out = (float*)d_out;

  char* ws = (char*)d_ws;
  size_t off = 0;
  auto alloc = [&](size_t bytes) {
    char* p = ws + off;
    off += (bytes + 255) & ~(size_t)255;
    return p;
  };
  unsigned short* x_bf  = (unsigned short*)alloc((size_t)M_SZ * KD * 2);
  unsigned short* wq_bf = (unsigned short*)alloc((size_t)N1 * KD * 2);
  unsigned short* wo_bf = (unsigned short*)alloc((size_t)DM * KD * 2);
  unsigned short* qkv   = (unsigned short*)alloc((size_t)M_SZ * N1 * 2);
  unsigned short* qb    = (unsigned short*)alloc((size_t)B_SZ * H_SZ * T_SZ * DH * 2);
  unsigned short* kbuf  = (unsigned short*)alloc((size_t)B_SZ * H_SZ * T_SZ * DH * 2);
  unsigned short* vt    = (unsigned short*)alloc((size_t)B_SZ * H_SZ * DH * T_SZ * 2);
  unsigned short* oflat = (unsigned short*)alloc((size_t)M_SZ * DM * 2);
  float* cosb = (float*)alloc((size_t)T_SZ * 64 * 4);
  float* sinb = (float*)alloc((size_t)T_SZ * 64 * 4);

  cast_f32_bf16<<<8192, 256, 0, stream>>>(x, x_bf, M_SZ * KD / 4);
  cast_f32_bf16<<<12288, 256, 0, stream>>>(w_qkv, wq_bf, N1 * KD / 4);
  cast_f32_bf16<<<4096, 256, 0, stream>>>(w_out, wo_bf, DM * KD / 4);
  rope_table<<<T_SZ, 64, 0, stream>>>(cosb, sinb);

  // QKV projection: M=4096, N=6144 -> 16 x 24 = 384 blocks, 2 blocks/CU resident
  gemmv<256, 256, true><<<384, 512, 0, stream>>>(x_bf, wq_bf, qkv, N1, N1 / 256);

  rope_scatter_qk<<<16384, 256, 0, stream>>>(qkv, cosb, sinb, qb, kbuf);
  v_transpose<<<dim3(T_SZ / 32, 4, B_SZ * H_SZ), 256, 0, stream>>>(qkv, vt);

  attn_fwd2<<<dim3(16, 32), 256, 0, stream>>>(qb, kbuf, vt, oflat);

  // out projection: M=4096, N=2048 -> 32 x 8 = 256 blocks, 3 blocks/CU resident
  gemmv<128, 256, false><<<256, 512, 0, stream>>>(oflat, wo_bf, out, DM, DM / 256);
}